// Round 1
// baseline (173.637 us; speedup 1.0000x reference)
//
#include <hip/hip_runtime.h>

#define NB 512
#define NT 512
#define NL 64
#define L2E 1.4426950408889634f   // log2(e)
#define LN2 0.6931471805599453f   // ln(2)

typedef _Float16 h2 __attribute__((ext_vector_type(2)));

__global__ void zero_out_kernel(float* out) { *out = 0.0f; }

__device__ __forceinline__ float dot2f(h2 a, h2 b, float c) {
#if __has_builtin(__builtin_amdgcn_fdot2)
  return __builtin_amdgcn_fdot2(a, b, c, false);
#else
  return fmaf((float)a[0], (float)b[0], fmaf((float)a[1], (float)b[1], c));
#endif
}

__device__ __forceinline__ h2 bch2(unsigned u) { return __builtin_bit_cast(h2, u); }

// R11: replace the per-step LDS write+8*ds_read_b128 broadcast (the ~400+cyc
// lgkmcnt stall dominating the 755-cyc serial step) with an all-register XOR
// butterfly:
//   lane (r=j>>4, c=j&15) gathers its row-of-16 state via
//     quad_perm 0xB1 (xor1) -> pack h2 -> quad_perm 0x4E (xor2)
//     -> ds_swizzle 0x101F (xor4) -> ds_swizzle 0x201F (xor8)
//   giving g[k] = s[16r + (c^k)] as 8 packed h2 regs (order is pure XOR, so
//   the per-lane ep fragments are loaded pre-permuted to match).
//   Each lane computes 4 row-partials (outputs j' = 16q+c, 32 dot2 total),
//   then a 2-level reduce-scatter (shfl_xor 16, shfl_xor 32 with slot
//   selects) lands y_j in lane j -- same lane<->state invariant as before.
// Everything else (mask ballots, exact integer-G 2^(127-e0) rescale, em
// prefetch ring, path score, fwd/bwd T/2 split, junction) kept verbatim.
__device__ __forceinline__ float matvec64(float hval, const h2 (&ep)[4][8],
                                          bool rb0, bool rb1) {
  unsigned hu = (unsigned)__builtin_bit_cast(unsigned short, (_Float16)hval);
  unsigned n1 = (unsigned)__builtin_amdgcn_mov_dpp((int)hu, 0xB1, 0xF, 0xF, true);
  unsigned p0 = hu | (n1 << 16);                                    // (c, c^1)
  unsigned p1 = (unsigned)__builtin_amdgcn_mov_dpp((int)p0, 0x4E, 0xF, 0xF, true); // (c^2,c^3)
  unsigned p2 = (unsigned)__builtin_amdgcn_ds_swizzle((int)p0, 0x101F); // (c^4,c^5)
  unsigned p3 = (unsigned)__builtin_amdgcn_ds_swizzle((int)p1, 0x101F); // (c^6,c^7)
  unsigned p4 = (unsigned)__builtin_amdgcn_ds_swizzle((int)p0, 0x201F); // (c^8,c^9)
  unsigned p5 = (unsigned)__builtin_amdgcn_ds_swizzle((int)p1, 0x201F); // (c^10,c^11)
  unsigned p6 = (unsigned)__builtin_amdgcn_ds_swizzle((int)p2, 0x201F); // (c^12,c^13)
  unsigned p7 = (unsigned)__builtin_amdgcn_ds_swizzle((int)p3, 0x201F); // (c^14,c^15)
  float P[4];
#pragma unroll
  for (int q = 0; q < 4; ++q) {
    float a = dot2f(bch2(p0), ep[q][0], 0.0f);
    a = dot2f(bch2(p1), ep[q][1], a);
    a = dot2f(bch2(p2), ep[q][2], a);
    a = dot2f(bch2(p3), ep[q][3], a);
    float bq = dot2f(bch2(p4), ep[q][4], 0.0f);
    bq = dot2f(bch2(p5), ep[q][5], bq);
    bq = dot2f(bch2(p6), ep[q][6], bq);
    bq = dot2f(bch2(p7), ep[q][7], bq);
    P[q] = a + bq;
  }
  // reduce-scatter across the 4 row-groups: final slot q == r.
  float qa = rb0 ? P[1] : P[0];
  float sa = rb0 ? P[0] : P[1];
  float qb = rb0 ? P[3] : P[2];
  float sb = rb0 ? P[2] : P[3];
  qa += __shfl_xor(sa, 16, 64);
  qb += __shfl_xor(sb, 16, 64);
  float qq = rb1 ? qb : qa;
  float ss = rb1 ? qa : qb;
  return qq + __shfl_xor(ss, 32, 64);
}

__global__
__attribute__((amdgpu_flat_work_group_size(128, 128), amdgpu_waves_per_eu(1, 1)))
void crf_nll_kernel(
    const float* __restrict__ emission,     // B,T,L
    const int*   __restrict__ target,       // B,T
    const float* __restrict__ mask,         // B,T
    const float* __restrict__ start_trans,  // L
    const float* __restrict__ trans,        // L,L
    const float* __restrict__ end_trans,    // L
    float* __restrict__ out)
{
  const int b = blockIdx.x;
  const int tid = threadIdx.x;
  const int wv = tid >> 6;            // 0 = forward, 1 = backward
  const int j = tid & 63;
  const int r = j >> 4;
  const int c = j & 15;
  const bool rb0 = (r & 1) != 0;
  const bool rb1 = (r & 2) != 0;

  const float* em_b = emission + (size_t)b * NT * NL;
  const float* mk_b = mask + (size_t)b * NT;
  const int*   tg_b = target + (size_t)b * NT;

  __shared__ float fF[NL], fB[NL];
  __shared__ float psS[2];
  __shared__ int   GS[2];

  // ------- path score: wave wv covers chunks [4wv, 4wv+4) = its T half -----
  float ps = 0.0f;
  #pragma unroll
  for (int cc = 4 * wv; cc < 4 * wv + 4; ++cc) {
    int t = cc * 64 + j;
    int cur = tg_b[t];
    float m  = mk_b[t];
    float mn = (t + 1 < NT) ? mk_b[t + 1] : 0.0f;
    if (t == 0) {
      ps += start_trans[cur] + em_b[cur];
    } else {
      int prev = tg_b[t - 1];
      if (m > 0.5f)
        ps += trans[prev * NL + cur] + em_b[(size_t)t * NL + cur];
      if (m - mn > 0.5f)                 // end_mask = m_t & !m_{t+1}
        ps += end_trans[cur];
    }
  }
  #pragma unroll
  for (int off = 32; off; off >>= 1) ps += __shfl_down(ps, off, 64);

  const float endt = __builtin_amdgcn_exp2f(L2E * end_trans[j]);

  int G = 0;          // exact integer scale deficit (log2 units): true = s*2^G
  float s;

  if (wv == 0) {
    // ======================= FORWARD: t = 0..255 ===========================
    // ep[q][m] = (E[16r + (c^(2m))][16q+c], E[16r + ((c^(2m))^1)][16q+c])
    // pre-permuted to match the XOR gather order; trans is 16KB -> L2-hot.
    h2 ep[4][8];
    #pragma unroll
    for (int q = 0; q < 4; ++q) {
      const int col = 16 * q + c;
      #pragma unroll
      for (int m = 0; m < 8; ++m) {
        const int i0 = 16 * r + (c ^ (2 * m));
        const int i1 = i0 ^ 1;
        float e0 = __builtin_amdgcn_exp2f(L2E * trans[i0 * NL + col]);
        float e1 = __builtin_amdgcn_exp2f(L2E * trans[i1 * NL + col]);
        h2 v; v[0] = (_Float16)e0; v[1] = (_Float16)e1;
        ep[q][m] = v;
      }
    }
    s = __builtin_amdgcn_exp2f(L2E * (start_trans[j] + em_b[j]));  // t=0

    float pf[8];
    #pragma unroll
    for (int u = 0; u < 8; ++u) pf[u] = L2E * em_b[(size_t)u * NL + j];

    #pragma unroll 1
    for (int cc = 0; cc < 4; ++cc) {
      const int tb = cc * 64;
      float ml = mk_b[tb + j];
      int nidx = tb + j + 1;
      float mnext = (nidx < NT) ? mk_b[nidx] : 0.0f;
      unsigned long long cm = __ballot(ml > 0.5f);
      unsigned long long ce = __ballot(ml - mnext > 0.5f);
      if (cc == 0) { cm &= ~1ull; ce &= ~1ull; }  // t=0 handled by init

      #pragma unroll 1
      for (int i8 = 0; i8 < 64; i8 += 8) {
        #pragma unroll
        for (int u = 0; u < 8; ++u) {
          const int i = i8 + u;
          // off-chain: eem (endt folded), prefetch t+8
          float eemu = __builtin_amdgcn_exp2f(pf[u]);
          eemu = ((ce >> i) & 1) ? eemu * endt : eemu;
          int tp = tb + i + 8; if (tp > NT - 1) tp = NT - 1;
          pf[u] = L2E * em_b[(size_t)tp * NL + j];
          // chain: butterfly gather -> partial dots -> reduce-scatter
          float sm = matvec64(s, ep, rb0, rb1);
          unsigned e0 =
            (__builtin_amdgcn_readfirstlane(__float_as_uint(sm)) >> 23) & 0xffu;
          float scale = __uint_as_float((254u - e0) << 23);  // 2^(127-e0)
          float snew = (sm * scale) * eemu;
          float sold = s * scale;
          s = ((cm >> i) & 1) ? snew : sold;
          G += (int)e0 - 127;
        }
      }
    }
  } else {
    // ======================= BACKWARD: t = 511..256 ========================
    // ep[q][m] = (E[16q+c][16r + (c^(2m))], E[16q+c][16r + ((c^(2m))^1)])
    h2 ep[4][8];
    #pragma unroll
    for (int q = 0; q < 4; ++q) {
      const int rowi = 16 * q + c;
      #pragma unroll
      for (int m = 0; m < 8; ++m) {
        const int j0 = 16 * r + (c ^ (2 * m));
        const int j1 = j0 ^ 1;
        float e0 = __builtin_amdgcn_exp2f(L2E * trans[rowi * NL + j0]);
        float e1 = __builtin_amdgcn_exp2f(L2E * trans[rowi * NL + j1]);
        h2 v; v[0] = (_Float16)e0; v[1] = (_Float16)e1;
        ep[q][m] = v;
      }
    }
    s = 1.0f;                                   // v^T = 1^T

    float pf[8];                                 // pf[t&7] = l2e*em[t][j]
    #pragma unroll
    for (int u = 0; u < 8; ++u) pf[u] = L2E * em_b[(size_t)(504 + u) * NL + j];

    #pragma unroll 1
    for (int cc = 7; cc >= 4; --cc) {
      const int tb = cc * 64;
      float ml = mk_b[tb + j];
      int nidx = tb + j + 1;
      float mnext = (nidx < NT) ? mk_b[nidx] : 0.0f;
      unsigned long long cm = __ballot(ml > 0.5f);
      unsigned long long ce = __ballot(ml - mnext > 0.5f);

      #pragma unroll 1
      for (int i8 = 56; i8 >= 0; i8 -= 8) {
        #pragma unroll
        for (int u = 7; u >= 0; --u) {
          const int i = i8 + u;
          const int t = tb + i;                  // t & 7 == u
          // off-chain: wmul = eem^{m} * endt^{e}, prefetch t-8
          float eemu = __builtin_amdgcn_exp2f(pf[u]);
          float wmul = ((cm >> i) & 1) ? eemu : 1.0f;
          wmul = ((ce >> i) & 1) ? wmul * endt : wmul;
          int tp = t - 8; if (tp < 0) tp = 0;
          pf[u] = L2E * em_b[(size_t)tp * NL + j];
          // chain: w = s*wmul -> gather -> dots -> reduce -> rescale
          float w = s * wmul;
          if ((cm >> i) & 1) {
            float sm = matvec64(w, ep, rb0, rb1);
            unsigned e0 =
              (__builtin_amdgcn_readfirstlane(__float_as_uint(sm)) >> 23) & 0xffu;
            float scale = __uint_as_float((254u - e0) << 23);  // 2^(127-e0)
            s = sm * scale;
            G += (int)e0 - 127;
          } else {
            s = w;                               // A_t = I (masked-out step)
          }
        }
      }
    }
  }

  // ---------------- junction: norm = log(v . q) + (Gf+Gb)*ln2 ---------------
  if (wv == 0) { fF[j] = s; if (j == 0) { psS[0] = ps; GS[0] = G; } }
  else         { fB[j] = s; if (j == 0) { psS[1] = ps; GS[1] = G; } }
  __syncthreads();
  if (wv == 0) {
    float prod = s * fB[j];
    #pragma unroll
    for (int off = 32; off; off >>= 1) prod += __shfl_xor(prod, off, 64);
    if (j == 0) {
      float norm = (__builtin_amdgcn_logf(prod) + (float)(GS[0] + GS[1])) * LN2;
      atomicAdd(out, (norm - psS[0] - psS[1]) * (1.0f / (float)NB));
    }
  }
}

extern "C" void kernel_launch(void* const* d_in, const int* in_sizes, int n_in,
                              void* d_out, int out_size, void* d_ws, size_t ws_size,
                              hipStream_t stream) {
  const float* emission    = (const float*)d_in[0];
  const int*   target      = (const int*)  d_in[1];
  const float* mask        = (const float*)d_in[2];
  const float* start_trans = (const float*)d_in[3];
  const float* trans       = (const float*)d_in[4];
  const float* end_trans   = (const float*)d_in[5];
  float* out = (float*)d_out;

  zero_out_kernel<<<1, 1, 0, stream>>>(out);
  crf_nll_kernel<<<NB, 128, 0, stream>>>(emission, target, mask, start_trans,
                                         trans, end_trans, out);
}

// Round 2
// 168.392 us; speedup vs baseline: 1.0311x; 1.0311x over previous
//
#include <hip/hip_runtime.h>

#define NB 512
#define NT 512
#define NL 64
#define L2E 1.4426950408889634f   // log2(e)
#define LN2 0.6931471805599453f   // ln(2)

typedef _Float16 h2 __attribute__((ext_vector_type(2)));

__global__ void zero_out_kernel(float* out) { *out = 0.0f; }

__device__ __forceinline__ float dot2f(h2 a, h2 b, float c) {
#if __has_builtin(__builtin_amdgcn_fdot2)
  return __builtin_amdgcn_fdot2(a, b, c, false);
#else
  return fmaf((float)a[0], (float)b[0], fmaf((float)a[1], (float)b[1], c));
#endif
}

__device__ __forceinline__ h2 bch2(unsigned u) { return __builtin_bit_cast(h2, u); }

// R12: R11's butterfly rebuilt with ZERO DS-pipe instructions on the chain.
// R11 post-mortem: ds_swizzle + __shfl_xor are the SAME ~130cy DS pipe as
// ds_read -- 4 serial traversals made the chain LONGER (872 vs 755 cy/step).
// Here every cross-lane move is VALU:
//   gather xor{1,2} via quad_perm DPP, xor{7,15} via row_half_mirror(0x141)/
//   row_mirror(0x140) DPP (7-i == i^7, 15-i == i^15; {1,2,7,15} spans 0..15);
//   reduce xor{16,32} via v_permlane16/32_swap_b32 self-swap:
//   swap(x,x) -> {dup-even, dup-odd} in either direction, so res0+res1 ==
//   x + x^d exactly -- direction-proof, association identical to R11.
// Everything else (mask ballots, exact integer-G 2^(127-e0) rescale, em
// prefetch ring, path score, fwd/bwd T/2 split, junction) kept verbatim.

__device__ __forceinline__ float pairsum16(float x) {
#if __has_builtin(__builtin_amdgcn_permlane16_swap)
  unsigned xu = __float_as_uint(x);
  auto rp = __builtin_amdgcn_permlane16_swap(xu, xu, false, false);
  return __uint_as_float(rp[0]) + __uint_as_float(rp[1]);
#else
  return x + __shfl_xor(x, 16, 64);
#endif
}

__device__ __forceinline__ float pairsum32(float x) {
#if __has_builtin(__builtin_amdgcn_permlane32_swap)
  unsigned xu = __float_as_uint(x);
  auto rp = __builtin_amdgcn_permlane32_swap(xu, xu, false, false);
  return __uint_as_float(rp[0]) + __uint_as_float(rp[1]);
#else
  return x + __shfl_xor(x, 32, 64);
#endif
}

// Gather pair order produced by the DPP mirror network: reg m holds
// (s[16r + (c ^ PX0[m])], s[16r + (c ^ PX1[m])]).
// p0=(0,1) p1=(2,3) p2=(7,6) p3=(5,4) p4=(15,14) p5=(13,12) p6=(8,9) p7=(10,11)

__device__ __forceinline__ float matvec64(float hval, const h2 (&ep)[4][8], int r) {
  unsigned hu = (unsigned)__builtin_bit_cast(unsigned short, (_Float16)hval);
  unsigned n1 = (unsigned)__builtin_amdgcn_mov_dpp((int)hu, 0xB1, 0xF, 0xF, true);  // xor1
  unsigned p0 = hu | (n1 << 16);
  unsigned p1 = (unsigned)__builtin_amdgcn_mov_dpp((int)p0, 0x4E, 0xF, 0xF, true);  // xor2
  unsigned p2 = (unsigned)__builtin_amdgcn_mov_dpp((int)p0, 0x141, 0xF, 0xF, true); // xor7
  unsigned p3 = (unsigned)__builtin_amdgcn_mov_dpp((int)p1, 0x141, 0xF, 0xF, true);
  unsigned p4 = (unsigned)__builtin_amdgcn_mov_dpp((int)p0, 0x140, 0xF, 0xF, true); // xor15
  unsigned p5 = (unsigned)__builtin_amdgcn_mov_dpp((int)p1, 0x140, 0xF, 0xF, true);
  unsigned p6 = (unsigned)__builtin_amdgcn_mov_dpp((int)p2, 0x140, 0xF, 0xF, true); // xor8
  unsigned p7 = (unsigned)__builtin_amdgcn_mov_dpp((int)p3, 0x140, 0xF, 0xF, true); // xor10
  float F[4];
#pragma unroll
  for (int q = 0; q < 4; ++q) {
    float a = dot2f(bch2(p0), ep[q][0], 0.0f);
    a = dot2f(bch2(p1), ep[q][1], a);
    a = dot2f(bch2(p2), ep[q][2], a);
    a = dot2f(bch2(p3), ep[q][3], a);
    float b = dot2f(bch2(p4), ep[q][4], 0.0f);
    b = dot2f(bch2(p5), ep[q][5], b);
    b = dot2f(bch2(p6), ep[q][6], b);
    b = dot2f(bch2(p7), ep[q][7], b);
    // (P + P^16) + (P^32 + P^48) -- same association as R11
    F[q] = pairsum32(pairsum16(a + b));
  }
  float ya = (r & 1) ? F[1] : F[0];
  float yb = (r & 1) ? F[3] : F[2];
  return (r & 2) ? yb : ya;
}

__global__
__attribute__((amdgpu_flat_work_group_size(128, 128), amdgpu_waves_per_eu(1, 1)))
void crf_nll_kernel(
    const float* __restrict__ emission,     // B,T,L
    const int*   __restrict__ target,       // B,T
    const float* __restrict__ mask,         // B,T
    const float* __restrict__ start_trans,  // L
    const float* __restrict__ trans,        // L,L
    const float* __restrict__ end_trans,    // L
    float* __restrict__ out)
{
  const int b = blockIdx.x;
  const int tid = threadIdx.x;
  const int wv = tid >> 6;            // 0 = forward, 1 = backward
  const int j = tid & 63;
  const int r = j >> 4;
  const int c = j & 15;

  const float* em_b = emission + (size_t)b * NT * NL;
  const float* mk_b = mask + (size_t)b * NT;
  const int*   tg_b = target + (size_t)b * NT;

  __shared__ float fF[NL], fB[NL];
  __shared__ float psS[2];
  __shared__ int   GS[2];

  constexpr int PX0[8] = {0, 2, 7, 5, 15, 13, 8, 10};
  constexpr int PX1[8] = {1, 3, 6, 4, 14, 12, 9, 11};

  // ------- path score: wave wv covers chunks [4wv, 4wv+4) = its T half -----
  float ps = 0.0f;
  #pragma unroll
  for (int cc = 4 * wv; cc < 4 * wv + 4; ++cc) {
    int t = cc * 64 + j;
    int cur = tg_b[t];
    float m  = mk_b[t];
    float mn = (t + 1 < NT) ? mk_b[t + 1] : 0.0f;
    if (t == 0) {
      ps += start_trans[cur] + em_b[cur];
    } else {
      int prev = tg_b[t - 1];
      if (m > 0.5f)
        ps += trans[prev * NL + cur] + em_b[(size_t)t * NL + cur];
      if (m - mn > 0.5f)                 // end_mask = m_t & !m_{t+1}
        ps += end_trans[cur];
    }
  }
  #pragma unroll
  for (int off = 32; off; off >>= 1) ps += __shfl_down(ps, off, 64);

  const float endt = __builtin_amdgcn_exp2f(L2E * end_trans[j]);

  int G = 0;          // exact integer scale deficit (log2 units): true = s*2^G
  float s;

  if (wv == 0) {
    // ======================= FORWARD: t = 0..255 ===========================
    // ep[q][m] matches the DPP mirror pair order (PX0/PX1); column 16q+c.
    h2 ep[4][8];
    #pragma unroll
    for (int q = 0; q < 4; ++q) {
      const int col = 16 * q + c;
      #pragma unroll
      for (int m = 0; m < 8; ++m) {
        const int i0 = 16 * r + (c ^ PX0[m]);
        const int i1 = 16 * r + (c ^ PX1[m]);
        float e0 = __builtin_amdgcn_exp2f(L2E * trans[i0 * NL + col]);
        float e1 = __builtin_amdgcn_exp2f(L2E * trans[i1 * NL + col]);
        h2 v; v[0] = (_Float16)e0; v[1] = (_Float16)e1;
        ep[q][m] = v;
      }
    }
    s = __builtin_amdgcn_exp2f(L2E * (start_trans[j] + em_b[j]));  // t=0

    float pf[8];
    #pragma unroll
    for (int u = 0; u < 8; ++u) pf[u] = L2E * em_b[(size_t)u * NL + j];

    #pragma unroll 1
    for (int cc = 0; cc < 4; ++cc) {
      const int tb = cc * 64;
      float ml = mk_b[tb + j];
      int nidx = tb + j + 1;
      float mnext = (nidx < NT) ? mk_b[nidx] : 0.0f;
      unsigned long long cm = __ballot(ml > 0.5f);
      unsigned long long ce = __ballot(ml - mnext > 0.5f);
      if (cc == 0) { cm &= ~1ull; ce &= ~1ull; }  // t=0 handled by init

      #pragma unroll 1
      for (int i8 = 0; i8 < 64; i8 += 8) {
        #pragma unroll
        for (int u = 0; u < 8; ++u) {
          const int i = i8 + u;
          // off-chain: eem (endt folded), prefetch t+8
          float eemu = __builtin_amdgcn_exp2f(pf[u]);
          eemu = ((ce >> i) & 1) ? eemu * endt : eemu;
          int tp = tb + i + 8; if (tp > NT - 1) tp = NT - 1;
          pf[u] = L2E * em_b[(size_t)tp * NL + j];
          // chain: DPP gather -> dots -> permlane reduce -> rescale -> select
          float sm = matvec64(s, ep, r);
          unsigned e0 =
            (__builtin_amdgcn_readfirstlane(__float_as_uint(sm)) >> 23) & 0xffu;
          float scale = __uint_as_float((254u - e0) << 23);  // 2^(127-e0)
          float snew = (sm * scale) * eemu;
          float sold = s * scale;
          s = ((cm >> i) & 1) ? snew : sold;
          G += (int)e0 - 127;
        }
      }
    }
  } else {
    // ======================= BACKWARD: t = 511..256 ========================
    // ep[q][m]: row 16q+c of trans, columns in DPP mirror pair order.
    h2 ep[4][8];
    #pragma unroll
    for (int q = 0; q < 4; ++q) {
      const int rowi = 16 * q + c;
      #pragma unroll
      for (int m = 0; m < 8; ++m) {
        const int j0 = 16 * r + (c ^ PX0[m]);
        const int j1 = 16 * r + (c ^ PX1[m]);
        float e0 = __builtin_amdgcn_exp2f(L2E * trans[rowi * NL + j0]);
        float e1 = __builtin_amdgcn_exp2f(L2E * trans[rowi * NL + j1]);
        h2 v; v[0] = (_Float16)e0; v[1] = (_Float16)e1;
        ep[q][m] = v;
      }
    }
    s = 1.0f;                                   // v^T = 1^T

    float pf[8];                                 // pf[t&7] = l2e*em[t][j]
    #pragma unroll
    for (int u = 0; u < 8; ++u) pf[u] = L2E * em_b[(size_t)(504 + u) * NL + j];

    #pragma unroll 1
    for (int cc = 7; cc >= 4; --cc) {
      const int tb = cc * 64;
      float ml = mk_b[tb + j];
      int nidx = tb + j + 1;
      float mnext = (nidx < NT) ? mk_b[nidx] : 0.0f;
      unsigned long long cm = __ballot(ml > 0.5f);
      unsigned long long ce = __ballot(ml - mnext > 0.5f);

      #pragma unroll 1
      for (int i8 = 56; i8 >= 0; i8 -= 8) {
        #pragma unroll
        for (int u = 7; u >= 0; --u) {
          const int i = i8 + u;
          const int t = tb + i;                  // t & 7 == u
          // off-chain: wmul = eem^{m} * endt^{e}, prefetch t-8
          float eemu = __builtin_amdgcn_exp2f(pf[u]);
          float wmul = ((cm >> i) & 1) ? eemu : 1.0f;
          wmul = ((ce >> i) & 1) ? wmul * endt : wmul;
          int tp = t - 8; if (tp < 0) tp = 0;
          pf[u] = L2E * em_b[(size_t)tp * NL + j];
          // chain: w = s*wmul -> gather -> dots -> reduce -> rescale
          float w = s * wmul;
          if ((cm >> i) & 1) {
            float sm = matvec64(w, ep, r);
            unsigned e0 =
              (__builtin_amdgcn_readfirstlane(__float_as_uint(sm)) >> 23) & 0xffu;
            float scale = __uint_as_float((254u - e0) << 23);  // 2^(127-e0)
            s = sm * scale;
            G += (int)e0 - 127;
          } else {
            s = w;                               // A_t = I (masked-out step)
          }
        }
      }
    }
  }

  // ---------------- junction: norm = log(v . q) + (Gf+Gb)*ln2 ---------------
  if (wv == 0) { fF[j] = s; if (j == 0) { psS[0] = ps; GS[0] = G; } }
  else         { fB[j] = s; if (j == 0) { psS[1] = ps; GS[1] = G; } }
  __syncthreads();
  if (wv == 0) {
    float prod = s * fB[j];
    #pragma unroll
    for (int off = 32; off; off >>= 1) prod += __shfl_xor(prod, off, 64);
    if (j == 0) {
      float norm = (__builtin_amdgcn_logf(prod) + (float)(GS[0] + GS[1])) * LN2;
      atomicAdd(out, (norm - psS[0] - psS[1]) * (1.0f / (float)NB));
    }
  }
}

extern "C" void kernel_launch(void* const* d_in, const int* in_sizes, int n_in,
                              void* d_out, int out_size, void* d_ws, size_t ws_size,
                              hipStream_t stream) {
  const float* emission    = (const float*)d_in[0];
  const int*   target      = (const int*)  d_in[1];
  const float* mask        = (const float*)d_in[2];
  const float* start_trans = (const float*)d_in[3];
  const float* trans       = (const float*)d_in[4];
  const float* end_trans   = (const float*)d_in[5];
  float* out = (float*)d_out;

  zero_out_kernel<<<1, 1, 0, stream>>>(out);
  crf_nll_kernel<<<NB, 128, 0, stream>>>(emission, target, mask, start_trans,
                                         trans, end_trans, out);
}